// Round 1
// 650.316 us; speedup vs baseline: 1.0106x; 1.0106x over previous
//
#include <hip/hip_runtime.h>
#include <math.h>

#define PI_F 3.14159265358979323846f
// Wave-level LDS sync: DS ops from one wave execute in order; waitcnt drains them,
// "memory" clobber stops compiler reordering. No s_barrier needed for wave-private data.
#define WSYNC() asm volatile("s_waitcnt lgkmcnt(0)" ::: "memory")

// ---------------- complex helpers ----------------
__device__ __forceinline__ float2 cmul(float2 a, float2 b) {      // a*b
    return make_float2(a.x * b.x - a.y * b.y, a.x * b.y + a.y * b.x);
}
__device__ __forceinline__ float2 cmulc(float2 a, float2 b) {     // a*conj(b)
    return make_float2(a.x * b.x + a.y * b.y, a.y * b.x - a.x * b.y);
}
__device__ __forceinline__ int digitrev4(int p) {                 // reverse 4 base-4 digits
    return ((p & 3) << 6) | (((p >> 2) & 3) << 4) | (((p >> 4) & 3) << 2) | ((p >> 6) & 3);
}
// XOR bank-swizzle within a 256-point line: logical element e lives at e ^ ((e>>4)&15).
// Involution. Makes every radix-4 stage's b64 access pattern exactly 4 lanes/bank-pair
// (the wave64 hardware minimum) for stages S=0..3 and for the 4-elem staging accesses.
__device__ __forceinline__ int SW(int i) { return i ^ ((i >> 4) & 15); }

// W_256^eu, ^2eu, ^3eu via one sincos + angle addition
__device__ __forceinline__ void tw3(int eu, float2& w1, float2& w2, float2& w3) {
    float sn, cs;
    __sincosf(-(2.0f * PI_F / 256.0f) * (float)eu, &sn, &cs);
    w1 = make_float2(cs, sn);
    w2 = cmul(w1, w1);
    w3 = cmul(w2, w1);
}

// ---------------- radix-4 butterfly cores (twiddle-free) ----------------
__device__ __forceinline__ void bfly4_fwd(float2 a0, float2 a1, float2 a2, float2 a3,
                                          float2& o0, float2& o1, float2& o2, float2& o3) {
    float2 t0 = make_float2(a0.x + a2.x, a0.y + a2.y);
    float2 t1 = make_float2(a0.x - a2.x, a0.y - a2.y);
    float2 t2 = make_float2(a1.x + a3.x, a1.y + a3.y);
    float2 u  = make_float2(a1.x - a3.x, a1.y - a3.y);
    float2 t3 = make_float2(u.y, -u.x);                 // -i*u
    o0 = make_float2(t0.x + t2.x, t0.y + t2.y);
    o1 = make_float2(t1.x + t3.x, t1.y + t3.y);
    o2 = make_float2(t0.x - t2.x, t0.y - t2.y);
    o3 = make_float2(t1.x - t3.x, t1.y - t3.y);
}
__device__ __forceinline__ void bfly4_inv(float2 a0, float2 a1, float2 a2, float2 a3,
                                          float2& o0, float2& o1, float2& o2, float2& o3) {
    float2 t0 = make_float2(a0.x + a2.x, a0.y + a2.y);
    float2 t1 = make_float2(a0.x - a2.x, a0.y - a2.y);
    float2 t2 = make_float2(a1.x + a3.x, a1.y + a3.y);
    float2 u  = make_float2(a1.x - a3.x, a1.y - a3.y);
    float2 t3 = make_float2(-u.y, u.x);                 // +i*u
    o0 = make_float2(t0.x + t2.x, t0.y + t2.y);
    o1 = make_float2(t1.x + t3.x, t1.y + t3.y);
    o2 = make_float2(t0.x - t2.x, t0.y - t2.y);
    o3 = make_float2(t1.x - t3.x, t1.y - t3.y);
}

// ---------------- radix-4 stages on a swizzled 256-line (lane j = butterfly j) ----------------
// Forward DIF stage S (h=4^S): natural in -> base-4 digit-reversed out over stages 3,2,1,0.
template<int S>
__device__ __forceinline__ void stage_fwd_j(float2* line, int j, float2 w1, float2 w2, float2 w3) {
    const int h = 1 << (2 * S);
    int k  = j & (h - 1);
    int i0 = ((j >> (2 * S)) << (2 * S + 2)) + k;
    int p0 = SW(i0), p1 = SW(i0 + h), p2 = SW(i0 + 2 * h), p3 = SW(i0 + 3 * h);
    float2 a0 = line[p0], a1 = line[p1], a2 = line[p2], a3 = line[p3];
    float2 o0, o1, o2, o3;
    bfly4_fwd(a0, a1, a2, a3, o0, o1, o2, o3);
    line[p0] = o0;
    line[p1] = cmul(o1, w1);
    line[p2] = cmul(o2, w2);
    line[p3] = cmul(o3, w3);
}
// Inverse DIT stage S: digit-reversed in -> natural out over stages 0,1,2,3. Unnormalized.
template<int S>
__device__ __forceinline__ void stage_inv_j(float2* line, int j, float2 w1, float2 w2, float2 w3) {
    const int h = 1 << (2 * S);
    int k  = j & (h - 1);
    int i0 = ((j >> (2 * S)) << (2 * S + 2)) + k;
    int p0 = SW(i0), p1 = SW(i0 + h), p2 = SW(i0 + 2 * h), p3 = SW(i0 + 3 * h);
    float2 b0 = line[p0];
    float2 b1 = cmulc(line[p1], w1);
    float2 b2 = cmulc(line[p2], w2);
    float2 b3 = cmulc(line[p3], w3);
    float2 o0, o1, o2, o3;
    bfly4_inv(b0, b1, b2, b3, o0, o1, o2, o3);
    line[p0] = o0; line[p1] = o1; line[p2] = o2; line[p3] = o3;
}

// gain of the (fftshift-space) reference at centered freq (fy, fx)
__device__ __forceinline__ float gain1(float fy, float fx, const float* sw) {
    float r2 = fy * fy + fx * fx;
    float theta = atan2f(fy, fx) + PI_F;
    int idx = ((int)floorf(theta * (4.0f / PI_F))) & 7;
    float wv = sw[idx];
    return (r2 > 1474.56f) ? wv : 1.0f;                 // r > 0.3*128, r^2 integer
}

// ---------------- gain LUT setup: lut2[w_stored][h_logical] (digit-reversed coords) ----------------
__global__ __launch_bounds__(256) void k_gain_lut(const float* __restrict__ wts, float* __restrict__ lut2) {
    __shared__ float sw[8];
    int h = threadIdx.x, w = blockIdx.x;
    if (h < 8) sw[h] = wts[h];
    __syncthreads();
    int kw = digitrev4(w), kh = digitrev4(h);
    float fx  = (kw < 128) ? (float)kw : (float)(kw - 256);
    float fx2 = (kw == 128) ? -128.0f : -fx;
    float fy  = (kh < 128) ? (float)kh : (float)(kh - 256);
    float fy2 = (kh == 128) ? -128.0f : -fy;
    float g1 = gain1(fy, fx, sw);
    float g2 = gain1(fy2, fx2, sw);                     // symmetrize -> real filter
    lut2[w * 256 + h] = (1.0f + 0.5f * (g1 + g2)) * (1.0f / 65536.0f);
}

// ---------------- Pass 1: forward FFT along W. Wave owns 2 rows; no block barriers. ----------------
// Stage 0 fused into the global store (computed in registers).
__global__ __launch_bounds__(256) void k_row_fwd(const float* __restrict__ x, float* __restrict__ out) {
    __shared__ float2 lds[8][256];
    int t = threadIdx.x, wv = t >> 6, lane = t & 63;
    int gr = blockIdx.x * 8 + wv * 2;                   // global row id (pair-aligned, same image)
    int q = gr >> 8, h = gr & 255;
    int plane = ((q >> 7) << 8) + ((q & 127) << 1);
    size_t rA = ((size_t)plane << 16) + ((size_t)h << 8);
    size_t rB = rA + 65536;
    float2* L0 = lds[wv * 2];
    float2* L1 = lds[wv * 2 + 1];
    int w = lane * 4;
    float4 re0 = *(const float4*)(x + rA + w);
    float4 im0 = *(const float4*)(x + rB + w);
    float4 re1 = *(const float4*)(x + rA + 256 + w);
    float4 im1 = *(const float4*)(x + rB + 256 + w);
    // twiddles hoisted (lane-only dependence); sincos latency overlaps the loads
    float2 w31, w32, w33, w21, w22, w23, w11, w12, w13;
    tw3(lane,             w31, w32, w33);
    tw3((lane & 15) << 2, w21, w22, w23);
    tw3((lane & 3)  << 4, w11, w12, w13);
    int s0 = SW(w), s1 = SW(w + 1), s2 = SW(w + 2), s3 = SW(w + 3);
    L0[s0] = make_float2(re0.x, im0.x); L0[s1] = make_float2(re0.y, im0.y);
    L0[s2] = make_float2(re0.z, im0.z); L0[s3] = make_float2(re0.w, im0.w);
    L1[s0] = make_float2(re1.x, im1.x); L1[s1] = make_float2(re1.y, im1.y);
    L1[s2] = make_float2(re1.z, im1.z); L1[s3] = make_float2(re1.w, im1.w);
    WSYNC();
    stage_fwd_j<3>(L0, lane, w31, w32, w33); stage_fwd_j<3>(L1, lane, w31, w32, w33); WSYNC();
    stage_fwd_j<2>(L0, lane, w21, w22, w23); stage_fwd_j<2>(L1, lane, w21, w22, w23); WSYNC();
    stage_fwd_j<1>(L0, lane, w11, w12, w13); stage_fwd_j<1>(L1, lane, w11, w12, w13); WSYNC();
    // fused stage 0 (twiddle-free) -> global
    {
        float2 o0, o1, o2, o3;
        bfly4_fwd(L0[s0], L0[s1], L0[s2], L0[s3], o0, o1, o2, o3);
        *(float4*)(out + rA + w) = make_float4(o0.x, o1.x, o2.x, o3.x);
        *(float4*)(out + rB + w) = make_float4(o0.y, o1.y, o2.y, o3.y);
        bfly4_fwd(L1[s0], L1[s1], L1[s2], L1[s3], o0, o1, o2, o3);
        *(float4*)(out + rA + 256 + w) = make_float4(o0.x, o1.x, o2.x, o3.x);
        *(float4*)(out + rB + 256 + w) = make_float4(o0.y, o1.y, o2.y, o3.y);
    }
}

// ---------------- Pass 2: col FFT + gain + col IFFT. Wave owns 4 columns (processed in pairs). ----------------
template<bool USE_LUT>
__global__ __launch_bounds__(256) void k_col(float* __restrict__ data,
                                             const float* __restrict__ lut2,
                                             const float* __restrict__ wts) {
    __shared__ float2 tile[16][256];                    // 32 KiB exactly -> 5 blocks/CU
    int t = threadIdx.x;
    int q = blockIdx.x >> 4, wt = blockIdx.x & 15, w0 = wt * 16;
    int plane = ((q >> 7) << 8) + ((q & 127) << 1);
    size_t baseA = ((size_t)plane << 16) + (size_t)w0;
    size_t baseB = baseA + 65536;
    int c0 = (t & 3) * 4, h0 = (t >> 2) * 4;
    int wv = t >> 6, lane = t & 63;
    int i0 = lane * 4;

    // -------- fallback gains (no workspace): stash wts in tile scratch, compute to regs --------
    float4 gAr[2], gBr[2];
    if (!USE_LUT) {
        if (t < 8) ((float*)tile)[t] = wts[t];
        __syncthreads();
        const float* swp = (const float*)tile;
#pragma unroll
        for (int cp = 0; cp < 2; ++cp) {
#pragma unroll
            for (int cc = 0; cc < 2; ++cc) {
                int col = wv * 4 + cp * 2 + cc;
                int kw = digitrev4(w0 + col);
                float fx  = (kw < 128) ? (float)kw : (float)(kw - 256);
                float fx2 = (kw == 128) ? -128.0f : -fx;
                float4 g;
#pragma unroll
                for (int d = 0; d < 4; ++d) {
                    int kh = digitrev4(i0 + d);
                    float fy  = (kh < 128) ? (float)kh : (float)(kh - 256);
                    float fy2 = (kh == 128) ? -128.0f : -fy;
                    float g1v = gain1(fy, fx, swp);
                    float g2v = gain1(fy2, fx2, swp);
                    (&g.x)[d] = (1.0f + 0.5f * (g1v + g2v)) * (1.0f / 65536.0f);
                }
                if (cc == 0) gAr[cp] = g; else gBr[cp] = g;
            }
        }
        __syncthreads();
    }

    // -------- staging in: thread -> cols c0..c0+3, rows h0..h0+3 (b64 LDS writes, swizzled) --------
    {
        float4 reR[4], imR[4];
#pragma unroll
        for (int r = 0; r < 4; ++r) {
            reR[r] = *(const float4*)(data + baseA + (size_t)(h0 + r) * 256 + c0);
            imR[r] = *(const float4*)(data + baseB + (size_t)(h0 + r) * 256 + c0);
        }
#pragma unroll
        for (int r = 0; r < 4; ++r) {
            int p = SW(h0 + r);
#pragma unroll
            for (int k = 0; k < 4; ++k)
                tile[c0 + k][p] = make_float2((&reR[r].x)[k], (&imR[r].x)[k]);
        }
    }
    __syncthreads();

    // -------- wave-private column FFTs: lane = butterfly j, two lines interleaved per sync --------
    float2 w31, w32, w33, w21, w22, w23, w11, w12, w13;
    tw3(lane,             w31, w32, w33);
    tw3((lane & 15) << 2, w21, w22, w23);
    tw3((lane & 3)  << 4, w11, w12, w13);
    int p0 = SW(i0), p1 = SW(i0 + 1), p2 = SW(i0 + 2), p3 = SW(i0 + 3);
#pragma unroll
    for (int cp = 0; cp < 2; ++cp) {
        int colA = wv * 4 + cp * 2, colB = colA + 1;
        float2* LA = tile[colA];
        float2* LB = tile[colB];
        float4 gA, gB;
        if (USE_LUT) {
            gA = *(const float4*)(lut2 + (size_t)(w0 + colA) * 256 + i0);
            gB = *(const float4*)(lut2 + (size_t)(w0 + colB) * 256 + i0);
        } else {
            gA = gAr[cp]; gB = gBr[cp];
        }
        stage_fwd_j<3>(LA, lane, w31, w32, w33); stage_fwd_j<3>(LB, lane, w31, w32, w33); WSYNC();
        stage_fwd_j<2>(LA, lane, w21, w22, w23); stage_fwd_j<2>(LB, lane, w21, w22, w23); WSYNC();
        stage_fwd_j<1>(LA, lane, w11, w12, w13); stage_fwd_j<1>(LB, lane, w11, w12, w13); WSYNC();
        // fused fwd0 + gain + inv0 (stage-0 butterfly j covers logical elems 4j..4j+3 = LUT order)
        {
            float2 o0, o1, o2, o3, r0, r1, r2, r3;
            bfly4_fwd(LA[p0], LA[p1], LA[p2], LA[p3], o0, o1, o2, o3);
            o0.x *= gA.x; o0.y *= gA.x; o1.x *= gA.y; o1.y *= gA.y;
            o2.x *= gA.z; o2.y *= gA.z; o3.x *= gA.w; o3.y *= gA.w;
            bfly4_inv(o0, o1, o2, o3, r0, r1, r2, r3);
            LA[p0] = r0; LA[p1] = r1; LA[p2] = r2; LA[p3] = r3;
            bfly4_fwd(LB[p0], LB[p1], LB[p2], LB[p3], o0, o1, o2, o3);
            o0.x *= gB.x; o0.y *= gB.x; o1.x *= gB.y; o1.y *= gB.y;
            o2.x *= gB.z; o2.y *= gB.z; o3.x *= gB.w; o3.y *= gB.w;
            bfly4_inv(o0, o1, o2, o3, r0, r1, r2, r3);
            LB[p0] = r0; LB[p1] = r1; LB[p2] = r2; LB[p3] = r3;
        }
        WSYNC();
        stage_inv_j<1>(LA, lane, w11, w12, w13); stage_inv_j<1>(LB, lane, w11, w12, w13); WSYNC();
        stage_inv_j<2>(LA, lane, w21, w22, w23); stage_inv_j<2>(LB, lane, w21, w22, w23); WSYNC();
        stage_inv_j<3>(LA, lane, w31, w32, w33); stage_inv_j<3>(LB, lane, w31, w32, w33); WSYNC();
    }
    __syncthreads();

    // -------- staging out (mirror of staging in) --------
    {
#pragma unroll
        for (int r = 0; r < 4; ++r) {
            int p = SW(h0 + r);
            float2 v0 = tile[c0 + 0][p], v1 = tile[c0 + 1][p];
            float2 v2 = tile[c0 + 2][p], v3 = tile[c0 + 3][p];
            *(float4*)(data + baseA + (size_t)(h0 + r) * 256 + c0) = make_float4(v0.x, v1.x, v2.x, v3.x);
            *(float4*)(data + baseB + (size_t)(h0 + r) * 256 + c0) = make_float4(v0.y, v1.y, v2.y, v3.y);
        }
    }
}

// ---------------- Pass 3: inverse FFT along W. Wave owns 2 rows; stage 0 fused with the load. ----------------
__global__ __launch_bounds__(256) void k_row_inv(float* __restrict__ data) {
    __shared__ float2 lds[8][256];
    int t = threadIdx.x, wv = t >> 6, lane = t & 63;
    int gr = blockIdx.x * 8 + wv * 2;
    int q = gr >> 8, h = gr & 255;
    int plane = ((q >> 7) << 8) + ((q & 127) << 1);
    size_t rA = ((size_t)plane << 16) + ((size_t)h << 8);
    size_t rB = rA + 65536;
    float2* L0 = lds[wv * 2];
    float2* L1 = lds[wv * 2 + 1];
    int w = lane * 4;
    float4 re0 = *(const float4*)(data + rA + w);
    float4 im0 = *(const float4*)(data + rB + w);
    float4 re1 = *(const float4*)(data + rA + 256 + w);
    float4 im1 = *(const float4*)(data + rB + 256 + w);
    float2 w31, w32, w33, w21, w22, w23, w11, w12, w13;
    tw3(lane,             w31, w32, w33);
    tw3((lane & 15) << 2, w21, w22, w23);
    tw3((lane & 3)  << 4, w11, w12, w13);
    int s0 = SW(w), s1 = SW(w + 1), s2 = SW(w + 2), s3 = SW(w + 3);
    // fused inverse stage 0 (twiddle-free) from the just-loaded registers
    {
        float2 o0, o1, o2, o3;
        bfly4_inv(make_float2(re0.x, im0.x), make_float2(re0.y, im0.y),
                  make_float2(re0.z, im0.z), make_float2(re0.w, im0.w), o0, o1, o2, o3);
        L0[s0] = o0; L0[s1] = o1; L0[s2] = o2; L0[s3] = o3;
        bfly4_inv(make_float2(re1.x, im1.x), make_float2(re1.y, im1.y),
                  make_float2(re1.z, im1.z), make_float2(re1.w, im1.w), o0, o1, o2, o3);
        L1[s0] = o0; L1[s1] = o1; L1[s2] = o2; L1[s3] = o3;
    }
    WSYNC();
    stage_inv_j<1>(L0, lane, w11, w12, w13); stage_inv_j<1>(L1, lane, w11, w12, w13); WSYNC();
    stage_inv_j<2>(L0, lane, w21, w22, w23); stage_inv_j<2>(L1, lane, w21, w22, w23); WSYNC();
    stage_inv_j<3>(L0, lane, w31, w32, w33); stage_inv_j<3>(L1, lane, w31, w32, w33); WSYNC();
    float2 a0 = L0[s0], a1 = L0[s1], a2 = L0[s2], a3 = L0[s3];
    float2 b0 = L1[s0], b1 = L1[s1], b2 = L1[s2], b3 = L1[s3];
    *(float4*)(data + rA + w)       = make_float4(a0.x, a1.x, a2.x, a3.x);   // re -> ch 2c
    *(float4*)(data + rB + w)       = make_float4(a0.y, a1.y, a2.y, a3.y);   // im -> ch 2c+1
    *(float4*)(data + rA + 256 + w) = make_float4(b0.x, b1.x, b2.x, b3.x);
    *(float4*)(data + rB + 256 + w) = make_float4(b0.y, b1.y, b2.y, b3.y);
}

extern "C" void kernel_launch(void* const* d_in, const int* in_sizes, int n_in,
                              void* d_out, int out_size, void* d_ws, size_t ws_size,
                              hipStream_t stream) {
    const float* x   = (const float*)d_in[0];
    const float* wts = (const float*)d_in[1];
    float* out = (float*)d_out;
    (void)in_sizes; (void)n_in; (void)out_size;
    bool use_lut = (ws_size >= 256 * 256 * sizeof(float)) && (d_ws != nullptr);
    if (use_lut) {
        k_gain_lut<<<256, 256, 0, stream>>>(wts, (float*)d_ws);
    }
    // 512 image-pairs (B=4, C=256 paired), H=W=256; 131072 rows total, 8 per block
    k_row_fwd<<<16384, 256, 0, stream>>>(x, out);
    if (use_lut) {
        k_col<true><<<8192, 256, 0, stream>>>(out, (const float*)d_ws, wts);
    } else {
        k_col<false><<<8192, 256, 0, stream>>>(out, nullptr, wts);
    }
    k_row_inv<<<16384, 256, 0, stream>>>(out);
}